// Round 10
// baseline (332.503 us; speedup 1.0000x reference)
//
#include <hip/hip_runtime.h>
#include <hip/hip_fp16.h>
#include <stdint.h>

typedef unsigned short u16;
typedef int i32x4 __attribute__((ext_vector_type(4)));

#define DDIM 1024
#define FDIM 2048
#define NEXP 8
#define RT_TILES 72      /* routed row tiles: 9216/128 */
#define SHOFF 9216       /* start row of shared-expert segment */
#define RCAP 13312       /* 9216 routed (padded) + 4096 shared rows */
#define NRT 104          /* RCAP/128 row tiles */

// meta: [0..7] counts, [8..15] base[e], [16] total_padded, [30] dtype flag (1=fp32 inputs)

__device__ inline float bf2f(u16 u) {
    union { unsigned int i; float f; } v; v.i = ((unsigned int)u) << 16; return v.f;
}
__device__ inline u16 f2bf(float f) {
    union { float f; unsigned int i; } v; v.f = f;
    unsigned int lsb = (v.i >> 16) & 1u;
    return (u16)((v.i + 0x7fffu + lsb) >> 16);
}
__device__ inline int q8(float v, float inv) {
    int x = (int)rintf(v * inv);
    return x < -127 ? -127 : (x > 127 ? 127 : x);
}

typedef const __attribute__((address_space(1))) void gas_void;
typedef __attribute__((address_space(3))) void las_void;
#define GLL16(g, l) __builtin_amdgcn_global_load_lds((gas_void*)(g), (las_void*)(l), 16, 0, 0)

// Per-block dtype detect over first 1024 halfwords of x.
__device__ inline int detect_inline(const u16* __restrict__ x, int* sh) {
    if (threadIdx.x == 0) *sh = 0;
    __syncthreads();
    const int per = 1024 / blockDim.x;
    int bad = 0;
    for (int i = 0; i < per; i++) {
        u16 v = x[threadIdx.x * per + i];
        if (((v >> 7) & 0xFF) >= 0x8F) bad++;
    }
    if (bad) atomicAdd(sh, bad);
    __syncthreads();
    return (*sh > 32) ? 1 : 0;
}

// ---------------- Router: 16 tokens/block, logits -> top2 --------------------
__global__ __launch_bounds__(256) void router_kernel(
    const void* __restrict__ x_, const void* __restrict__ rw_, const void* __restrict__ rb_,
    float* __restrict__ top_w, int* __restrict__ top_idx)
{
    __shared__ float rws[NEXP * DDIM];  // 32 KB fp32
    __shared__ int scnt;
    const int tid = threadIdx.x;
    const int flag = detect_inline((const u16*)x_, &scnt);

    if (!flag) {
        const ushort4* rwv = (const ushort4*)rw_;
        #pragma unroll
        for (int i = 0; i < 8; i++) {
            int idx = tid + i * 256;
            ushort4 h = rwv[idx];
            rws[idx * 4 + 0] = bf2f(h.x); rws[idx * 4 + 1] = bf2f(h.y);
            rws[idx * 4 + 2] = bf2f(h.z); rws[idx * 4 + 3] = bf2f(h.w);
        }
    } else {
        const float4* rwv = (const float4*)rw_;
        #pragma unroll
        for (int i = 0; i < 8; i++) {
            int idx = tid + i * 256;
            float4 f = rwv[idx];
            rws[idx * 4 + 0] = f.x; rws[idx * 4 + 1] = f.y;
            rws[idx * 4 + 2] = f.z; rws[idx * 4 + 3] = f.w;
        }
    }
    __syncthreads();

    const int wave = tid >> 6, lane = tid & 63;

    for (int sub = 0; sub < 4; sub++) {
        const int t = blockIdx.x * 16 + wave * 4 + sub;
        float xv[16];
        if (!flag) {
            const u16* xr = (const u16*)x_ + (size_t)t * DDIM + lane * 16;
            uint4 p0 = *(const uint4*)(xr);
            uint4 p1 = *(const uint4*)(xr + 8);
            #pragma unroll
            for (int d = 0; d < 8; d++) xv[d]     = bf2f(((const u16*)&p0)[d]);
            #pragma unroll
            for (int d = 0; d < 8; d++) xv[d + 8] = bf2f(((const u16*)&p1)[d]);
        } else {
            const float4* xr = (const float4*)((const float*)x_ + (size_t)t * DDIM + lane * 16);
            #pragma unroll
            for (int c = 0; c < 4; c++) {
                float4 f = xr[c];
                xv[c * 4 + 0] = f.x; xv[c * 4 + 1] = f.y;
                xv[c * 4 + 2] = f.z; xv[c * 4 + 3] = f.w;
            }
        }

        float acc[NEXP];
        #pragma unroll
        for (int e = 0; e < NEXP; e++) {
            const float* wr = &rws[e * DDIM + lane * 16];
            float s = 0.f;
            #pragma unroll
            for (int d = 0; d < 16; d++) s += xv[d] * wr[d];
            acc[e] = s;
        }
        #pragma unroll
        for (int e = 0; e < NEXP; e++) {
            #pragma unroll
            for (int off = 32; off > 0; off >>= 1)
                acc[e] += __shfl_xor(acc[e], off, 64);
        }
        if (lane == 0) {
            float lg[NEXP];
            #pragma unroll
            for (int e = 0; e < NEXP; e++) {
                float b = flag ? ((const float*)rb_)[e] : bf2f(((const u16*)rb_)[e]);
                lg[e] = acc[e] + b;
            }
            int i0 = 0;
            #pragma unroll
            for (int e = 1; e < NEXP; e++) if (lg[e] > lg[i0]) i0 = e;
            int i1 = (i0 == 0) ? 1 : 0;
            #pragma unroll
            for (int e = 0; e < NEXP; e++) if (e != i0 && lg[e] > lg[i1]) i1 = e;
            float e1 = __expf(lg[i1] - lg[i0]);
            float w0 = 1.f / (1.f + e1);
            float w1 = e1 / (1.f + e1);
            top_w[2 * t] = w0;  top_w[2 * t + 1] = w1;
            top_idx[2 * t] = i0; top_idx[2 * t + 1] = i1;
        }
    }
}

// -------- Rank: prefix-sum rows per expert; publishes dtype flag --------
__global__ __launch_bounds__(1024) void rank_kernel(
    const u16* __restrict__ x, const int* __restrict__ top_idx,
    int* __restrict__ tok_rows, int* __restrict__ meta)
{
    __shared__ int wsum[16][NEXP];
    __shared__ int wbase[16][NEXP];
    __shared__ int scnt;
    const int tid = threadIdx.x, lane = tid & 63, wave = tid >> 6;

    const int flag = detect_inline(x, &scnt);
    if (tid == 0) meta[30] = flag;

    const int4* tp = (const int4*)(top_idx + tid * 8);
    int4 v0 = tp[0], v1 = tp[1];
    int e[8] = { v0.x, v0.y, v0.z, v0.w, v1.x, v1.y, v1.z, v1.w };

    int tcnt[NEXP];
    #pragma unroll
    for (int en = 0; en < NEXP; en++) tcnt[en] = 0;
    #pragma unroll
    for (int j = 0; j < 8; j++)
        #pragma unroll
        for (int en = 0; en < NEXP; en++) tcnt[en] += (e[j] == en);

    int excl[NEXP];
    #pragma unroll
    for (int en = 0; en < NEXP; en++) {
        int v = tcnt[en];
        #pragma unroll
        for (int off = 1; off < 64; off <<= 1) {
            int u = __shfl_up(v, off, 64);
            if (lane >= off) v += u;
        }
        excl[en] = v - tcnt[en];
        if (lane == 63) wsum[wave][en] = v;
    }
    __syncthreads();
    if (tid < NEXP) {
        int s = 0;
        for (int w = 0; w < 16; w++) { int c = wsum[w][tid]; wbase[w][tid] = s; s += c; }
        meta[tid] = s;
    }
    __syncthreads();
    if (tid == 0) {
        int b = 0;
        for (int en = 0; en < NEXP; en++) {
            meta[8 + en] = b;
            b += ((meta[en] + 127) >> 7) << 7;
        }
        meta[16] = b;
    }
    __syncthreads();

    int cur[NEXP];
    #pragma unroll
    for (int en = 0; en < NEXP; en++) cur[en] = meta[8 + en] + wbase[wave][en] + excl[en];

    int r[8];
    #pragma unroll
    for (int j = 0; j < 8; j++) {
        int rr = 0;
        #pragma unroll
        for (int en = 0; en < NEXP; en++)
            if (e[j] == en) { rr = cur[en]; cur[en] = rr + 1; }
        r[j] = rr;
    }
    int4* rp = (int4*)(tok_rows + tid * 8);
    rp[0] = make_int4(r[0], r[1], r[2], r[3]);
    rp[1] = make_int4(r[4], r[5], r[6], r[7]);
}

// -------- Gather + per-token int8 quantize: x rows -> xq + sxa --------
__global__ __launch_bounds__(128) void gather_q_kernel(
    const void* __restrict__ x_, const int* __restrict__ tok_rows,
    char* __restrict__ xq, float* __restrict__ sxa, const int* __restrict__ meta)
{
    __shared__ float red[128];
    const int t = blockIdx.x, tid = threadIdx.x;
    const int r0 = tok_rows[2 * t], r1 = tok_rows[2 * t + 1];

    float v[8];
    if (!meta[30]) {
        uint4 p = ((const uint4*)((const u16*)x_ + (size_t)t * DDIM))[tid];
        #pragma unroll
        for (int d = 0; d < 8; d++) v[d] = bf2f(((const u16*)&p)[d]);
    } else {
        const float4* xf = (const float4*)((const float*)x_ + (size_t)t * DDIM);
        float4 a = xf[2 * tid], b = xf[2 * tid + 1];
        v[0] = a.x; v[1] = a.y; v[2] = a.z; v[3] = a.w;
        v[4] = b.x; v[5] = b.y; v[6] = b.z; v[7] = b.w;
    }
    float m = 0.f;
    #pragma unroll
    for (int d = 0; d < 8; d++) m = fmaxf(m, fabsf(v[d]));
    red[tid] = m;
    __syncthreads();
    for (int s = 64; s > 0; s >>= 1) {
        if (tid < s) red[tid] = fmaxf(red[tid], red[tid + s]);
        __syncthreads();
    }
    const float mx = fmaxf(red[0], 1e-8f);
    const float inv = 127.f / mx;

    uint2 u;
    u.x = (unsigned)(q8(v[0], inv) & 255) | ((unsigned)(q8(v[1], inv) & 255) << 8) |
          ((unsigned)(q8(v[2], inv) & 255) << 16) | ((unsigned)(q8(v[3], inv) & 255) << 24);
    u.y = (unsigned)(q8(v[4], inv) & 255) | ((unsigned)(q8(v[5], inv) & 255) << 8) |
          ((unsigned)(q8(v[6], inv) & 255) << 16) | ((unsigned)(q8(v[7], inv) & 255) << 24);

    ((uint2*)(xq + (size_t)r0 * DDIM))[tid] = u;
    ((uint2*)(xq + (size_t)r1 * DDIM))[tid] = u;
    ((uint2*)(xq + (size_t)(SHOFF + t) * DDIM))[tid] = u;
    if (tid == 0) {
        float s = mx / 127.f;
        sxa[r0] = s; sxa[r1] = s; sxa[SHOFF + t] = s;
    }
}

// -------- Weight int8 recovery, fp16-packed retention (exact; no spill) ------
// w = q*s exactly (int8 fake-quant). fp16 RTNE of w has rel err <= 2^-11, and
// the row max is computed in fp32 (exact), so round(fp16(w)*127/max) deviates
// from integer q by <= 127*2^-11 = 0.062 < 0.5 -> exact q recovery.
// NR rows/wave, NCH float4 chunks/row/lane; NR*NCH*2 packed regs (48 both paths).
template <int NCH, int NR>
__device__ inline void wquant_rows(const char* const* s, char* dst, float* sc,
                                   int flag, int lane)
{
    unsigned hp[NR][NCH * 2];
    float m[NR];
    #pragma unroll
    for (int r = 0; r < NR; r++) {
        float mm = 0.f;
        #pragma unroll
        for (int c = 0; c < NCH; c++) {
            float4 f;
            if (flag) {
                f = ((const float4*)s[r])[c * 64 + lane];
            } else {
                ushort4 h = ((const ushort4*)s[r])[c * 64 + lane];
                f.x = bf2f(h.x); f.y = bf2f(h.y); f.z = bf2f(h.z); f.w = bf2f(h.w);
            }
            mm = fmaxf(mm, fmaxf(fmaxf(fabsf(f.x), fabsf(f.y)),
                                 fmaxf(fabsf(f.z), fabsf(f.w))));
            __half2 p0 = __floats2half2_rn(f.x, f.y);
            __half2 p1 = __floats2half2_rn(f.z, f.w);
            hp[r][2 * c]     = *(unsigned*)&p0;
            hp[r][2 * c + 1] = *(unsigned*)&p1;
        }
        m[r] = mm;
    }
    #pragma unroll
    for (int off = 32; off > 0; off >>= 1) {
        #pragma unroll
        for (int r = 0; r < NR; r++) m[r] = fmaxf(m[r], __shfl_xor(m[r], off, 64));
    }
    #pragma unroll
    for (int r = 0; r < NR; r++) {
        m[r] = fmaxf(m[r], 1e-12f);
        if (lane == 0) sc[r] = m[r] / 127.f;
        const float inv = 127.f / m[r];
        #pragma unroll
        for (int c = 0; c < NCH; c++) {
            float2 f01 = __half22float2(*(__half2*)&hp[r][2 * c]);
            float2 f23 = __half22float2(*(__half2*)&hp[r][2 * c + 1]);
            unsigned u = (unsigned)(q8(f01.x, inv) & 255) |
                         ((unsigned)(q8(f01.y, inv) & 255) << 8) |
                         ((unsigned)(q8(f23.x, inv) & 255) << 16) |
                         ((unsigned)(q8(f23.y, inv) & 255) << 24);
            ((unsigned*)dst)[r * (NCH * 64) + c * 64 + lane] = u;
        }
    }
}

// Groups: up rows in groups of 6 (NCH=4), down rows in groups of 3 (NCH=8).
// 18432/6 = 3072 up groups + 9216/3 = 3072 down groups = 6144 -> 1536 blocks.
__global__ __launch_bounds__(256) void wquant_kernel(
    const void* __restrict__ w_up, const void* __restrict__ w_down,
    const void* __restrict__ sw_up, const void* __restrict__ sw_down,
    char* __restrict__ qup, char* __restrict__ qdn,
    float* __restrict__ su, float* __restrict__ sd, const int* __restrict__ meta)
{
    const int flag = meta[30];
    const size_t es = flag ? 4 : 2;
    const int lane = threadIdx.x & 63;
    const int g = blockIdx.x * 4 + (threadIdx.x >> 6);   // 0..6143
    const int UPG = 3072;

    if (g < UPG) {
        const int R0 = g * 6;
        const char* s[6];
        #pragma unroll
        for (int r = 0; r < 6; r++) {
            const int R = R0 + r;
            s[r] = (R < NEXP * FDIM)
                 ? (const char*)w_up  + (size_t)R * DDIM * es
                 : (const char*)sw_up + (size_t)(R - NEXP * FDIM) * DDIM * es;
        }
        wquant_rows<4, 6>(s, qup + (size_t)R0 * DDIM, su + R0, flag, lane);
    } else {
        const int R0 = (g - UPG) * 3;
        const char* s[3];
        #pragma unroll
        for (int r = 0; r < 3; r++) {
            const int R = R0 + r;
            s[r] = (R < NEXP * DDIM)
                 ? (const char*)w_down  + (size_t)R * FDIM * es
                 : (const char*)sw_down + (size_t)(R - NEXP * DDIM) * FDIM * es;
        }
        wquant_rows<8, 3>(s, qdn + (size_t)R0 * FDIM, sd + R0, flag, lane);
    }
}

// ------- Grouped int8 GEMM: 128x256 tile, BK=64, waves 64x128, dbuf GLL16 ----
// mfma_i32_16x16x64_i8, 32 MFMA per 12 ds_read_b128 per wave-iter (MFMA-bound).
// LDS slot s of row r holds global 16B chunk (s - (r>>1)) & 3 (conflict swizzle).
// XCD swizzle: L%8 owns a 13-rt band, ct outer / rt inner; grid = 8*13*NCT.
__global__ __launch_bounds__(256, 2) void moe_gemm_i8(
    const char* __restrict__ A, const char* __restrict__ Wq,
    const float* __restrict__ sa, const float* __restrict__ sw,
    u16* __restrict__ Cout, const int* __restrict__ meta, int N, int Kd, int act)
{
    const int L = blockIdx.y * gridDim.x + blockIdx.x;
    const int xcd = L & 7;
    const int jj = L >> 3;
    const int rt = xcd * 13 + (jj % 13);
    const int ct = jj / 13;

    int e;
    if (rt >= RT_TILES) {
        e = NEXP;
    } else {
        const int r0t = rt * 128;
        if (r0t >= meta[16]) return;
        e = 0;
        #pragma unroll
        for (int i = 1; i < NEXP; i++) if (r0t >= meta[8 + i]) e = i;
        if (r0t >= meta[8 + e] + meta[e]) return;
    }
    const char* Wb = Wq + (size_t)(e * N + ct * 256) * Kd;
    const float* swb = sw + e * N + ct * 256;

    __shared__ char As[2][128 * 64];   // 16 KB
    __shared__ char Bs[2][256 * 64];   // 32 KB

    const int tid = threadIdx.x;
    const int wave = tid >> 6, lane = tid & 63;
    const int wm = (wave >> 1) * 64;    // 0 / 64
    const int wn = (wave & 1) * 128;    // 0 / 128
    const int l16 = lane & 15;
    const int q = lane >> 4;
    const int slot = (q + (l16 >> 1)) & 3;

    // staging: each GLL inst covers 16 rows x 64 B; 4 lanes per row
    const int rsub = lane >> 2;                        // 0..15
    const int qs = ((lane & 3) - ((lane >> 3) & 3)) & 3;

    const char* Ag = A + (size_t)(rt * 128 + wave * 16 + rsub) * Kd + qs * 16;
    const char* Bg = Wb + (size_t)(wave * 16 + rsub) * Kd + qs * 16;
    const size_t rstep = (size_t)64 * Kd;

    i32x4 acc[4][8] = {};

#define STAGE(buf, off) do { \
        GLL16(Ag + (off),             &As[buf][wave * 1024]); \
        GLL16(Ag + (off) + rstep,     &As[buf][4096 + wave * 1024]); \
        GLL16(Bg + (off),             &Bs[buf][wave * 1024]); \
        GLL16(Bg + (off) + rstep,     &Bs[buf][4096 + wave * 1024]); \
        GLL16(Bg + (off) + 2 * rstep, &Bs[buf][8192 + wave * 1024]); \
        GLL16(Bg + (off) + 3 * rstep, &Bs[buf][12288 + wave * 1024]); \
    } while (0)

    STAGE(0, 0);
    __syncthreads();

    int cur = 0;
    for (int kk = 0; kk < Kd; kk += 64) {
        if (kk + 64 < Kd) STAGE(cur ^ 1, kk + 64);
        i32x4 af[4], bf[8];
        #pragma unroll
        for (int i = 0; i < 4; i++)
            af[i] = *(const i32x4*)&As[cur][(wm + i * 16 + l16) * 64 + slot * 16];
        #pragma unroll
        for (int j = 0; j < 8; j++)
            bf[j] = *(const i32x4*)&Bs[cur][(wn + j * 16 + l16) * 64 + slot * 16];
        #pragma unroll
        for (int i = 0; i < 4; i++)
            #pragma unroll
            for (int j = 0; j < 8; j++)
                acc[i][j] = __builtin_amdgcn_mfma_i32_16x16x64_i8(af[i], bf[j], acc[i][j], 0, 0, 0);
        __syncthreads();
        cur ^= 1;
    }
#undef STAGE

    // epilogue: C/D col = lane&15, row = q*4 + reg; dequant acc*sa[row]*sw[col]
    float sal[4][4];
    #pragma unroll
    for (int i = 0; i < 4; i++)
        #pragma unroll
        for (int rr = 0; rr < 4; rr++)
            sal[i][rr] = sa[rt * 128 + wm + i * 16 + q * 4 + rr];
    float swl[8];
    #pragma unroll
    for (int j = 0; j < 8; j++) swl[j] = swb[wn + j * 16 + l16];

    u16* Crow = Cout + (size_t)(rt * 128) * N + ct * 256;
    #pragma unroll
    for (int i = 0; i < 4; i++) {
        #pragma unroll
        for (int j = 0; j < 8; j++) {
            #pragma unroll
            for (int rr = 0; rr < 4; rr++) {
                const int row = wm + i * 16 + q * 4 + rr;
                const int col = wn + j * 16 + l16;
                float v = (float)acc[i][j][rr] * sal[i][rr] * swl[j];
                if (act) v = v / (1.f + __expf(-v));   // SiLU
                Crow[(size_t)row * N + col] = f2bf(v);
            }
        }
    }
}

// -------- h quantize: hg bf16 rows -> h8 int8 + sh (per gathered row) --------
__global__ __launch_bounds__(256) void hquant_kernel(
    const u16* __restrict__ hg, char* __restrict__ h8, float* __restrict__ sh,
    const int* __restrict__ meta)
{
    const int r = blockIdx.x;
    if (r >= meta[16] && r < SHOFF) return;   // skip inter-segment pad
    __shared__ float red[256];
    const int tid = threadIdx.x;
    const u16* row = hg + (size_t)r * FDIM;
    uint4 p = ((const uint4*)row)[tid];
    float v[8];
    #pragma unroll
    for (int d = 0; d < 8; d++) v[d] = bf2f(((const u16*)&p)[d]);
    float m = 0.f;
    #pragma unroll
    for (int d = 0; d < 8; d++) m = fmaxf(m, fabsf(v[d]));
    red[tid] = m;
    __syncthreads();
    for (int s = 128; s > 0; s >>= 1) {
        if (tid < s) red[tid] = fmaxf(red[tid], red[tid + s]);
        __syncthreads();
    }
    const float mx = fmaxf(red[0], 1e-8f);
    const float inv = 127.f / mx;
    if (tid == 0) sh[r] = mx / 127.f;
    uint2 u;
    u.x = (unsigned)(q8(v[0], inv) & 255) | ((unsigned)(q8(v[1], inv) & 255) << 8) |
          ((unsigned)(q8(v[2], inv) & 255) << 16) | ((unsigned)(q8(v[3], inv) & 255) << 24);
    u.y = (unsigned)(q8(v[4], inv) & 255) | ((unsigned)(q8(v[5], inv) & 255) << 8) |
          ((unsigned)(q8(v[6], inv) & 255) << 16) | ((unsigned)(q8(v[7], inv) & 255) << 24);
    ((uint2*)(h8 + (size_t)r * FDIM))[tid] = u;
}

// ---------------- Combine ----------------
__global__ __launch_bounds__(256) void combine_kernel(
    const u16* __restrict__ yg, const float* __restrict__ top_w,
    const int* __restrict__ tok_rows, void* __restrict__ out_, const int* __restrict__ meta)
{
    const int t = blockIdx.x;
    const int r0 = tok_rows[2 * t], r1 = tok_rows[2 * t + 1];
    const float w0 = top_w[2 * t], w1 = top_w[2 * t + 1];
    const int d = threadIdx.x * 4;
    ushort4 y0 = *(const ushort4*)(yg + (size_t)r0 * DDIM + d);
    ushort4 y1 = *(const ushort4*)(yg + (size_t)r1 * DDIM + d);
    ushort4 ys = *(const ushort4*)(yg + (size_t)(SHOFF + t) * DDIM + d);
    float o0 = w0 * bf2f(y0.x) + w1 * bf2f(y1.x) + bf2f(ys.x);
    float o1 = w0 * bf2f(y0.y) + w1 * bf2f(y1.y) + bf2f(ys.y);
    float o2 = w0 * bf2f(y0.z) + w1 * bf2f(y1.z) + bf2f(ys.z);
    float o3 = w0 * bf2f(y0.w) + w1 * bf2f(y1.w) + bf2f(ys.w);
    if (!meta[30]) {
        ushort4 o; o.x = f2bf(o0); o.y = f2bf(o1); o.z = f2bf(o2); o.w = f2bf(o3);
        *(ushort4*)((u16*)out_ + (size_t)t * DDIM + d) = o;
    } else {
        float4 o; o.x = o0; o.y = o1; o.z = o2; o.w = o3;
        *(float4*)((float*)out_ + (size_t)t * DDIM + d) = o;
    }
}

extern "C" void kernel_launch(void* const* d_in, const int* in_sizes, int n_in,
                              void* d_out, int out_size, void* d_ws, size_t ws_size,
                              hipStream_t stream) {
    const void* x       = d_in[0];
    const void* rw      = d_in[1];
    const void* rb      = d_in[2];
    const void* w_up    = d_in[3];
    const void* w_down  = d_in[4];
    const void* sw_up   = d_in[5];
    const void* sw_down = d_in[6];

    const int T = in_sizes[0] / DDIM;  // 4096

    char* ws = (char*)d_ws;
    int*   meta     = (int*)ws;
    float* top_w    = (float*)(ws + 1024);
    int*   top_idx  = (int*)(ws + 1024 + 8 * T);
    int*   tok_rows = (int*)(ws + 1024 + 16 * T);
    size_t off = 131072;
    u16*  yg = (u16*)(ws + off);            // down output (bf16)
    char* xq = (char*)(ws + off);           // aliased: xq dead before yg written
    off += (size_t)RCAP * DDIM * 2;
    u16*  hg = (u16*)(ws + off);            // up output (bf16)
    off += (size_t)RCAP * FDIM * 2;
    char* h8 = (char*)(ws + off);
    off += (size_t)RCAP * FDIM;
    char* qup = (char*)(ws + off);
    off += (size_t)(NEXP + 1) * FDIM * DDIM;
    char* qdn = (char*)(ws + off);
    off += (size_t)(NEXP + 1) * DDIM * FDIM;
    float* sxa = (float*)(ws + off); off += (size_t)RCAP * 4;
    float* sh  = (float*)(ws + off); off += (size_t)RCAP * 4;
    float* su  = (float*)(ws + off); off += (size_t)(NEXP + 1) * FDIM * 4;
    float* sd  = (float*)(ws + off); off += (size_t)(NEXP + 1) * DDIM * 4;

    router_kernel<<<T / 16, 256, 0, stream>>>(x, rw, rb, top_w, top_idx);
    rank_kernel<<<1, 1024, 0, stream>>>((const u16*)x, top_idx, tok_rows, meta);
    gather_q_kernel<<<T, 128, 0, stream>>>(x, tok_rows, xq, sxa, meta);
    wquant_kernel<<<1536, 256, 0, stream>>>(
        w_up, w_down, sw_up, sw_down, qup, qdn, su, sd, meta);

    // Up: [RCAP,1024]i8 x [9*2048,1024]i8 -> hg bf16 (SiLU fused)
    // grid 8x104 = 832 = 8 XCD * 13 rt * 8 ct  (matches L-decode)
    moe_gemm_i8<<<dim3(FDIM / 256, NRT), 256, 0, stream>>>(
        xq, qup, sxa, su, hg, meta, FDIM, DDIM, 1);
    hquant_kernel<<<RCAP, 256, 0, stream>>>(hg, h8, sh, meta);
    // Down: grid 4x104 = 416 = 8 XCD * 13 rt * 4 ct
    moe_gemm_i8<<<dim3(DDIM / 256, NRT), 256, 0, stream>>>(
        h8, qdn, sh, sd, yg, meta, DDIM, FDIM, 0);
    combine_kernel<<<T, 256, 0, stream>>>(yg, top_w, tok_rows, d_out, meta);
}

// Round 11
// 323.123 us; speedup vs baseline: 1.0290x; 1.0290x over previous
//
#include <hip/hip_runtime.h>
#include <stdint.h>

typedef unsigned short u16;
typedef int i32x4 __attribute__((ext_vector_type(4)));

#define DDIM 1024
#define FDIM 2048
#define NEXP 8
#define RT_TILES 72      /* routed row tiles: 9216/128 */
#define SHOFF 9216       /* start row of shared-expert segment */
#define RCAP 13312       /* 9216 routed (padded) + 4096 shared rows */
#define NRT 104          /* RCAP/128 row tiles */
#define UPROWS 16384     /* NEXP*FDIM routed up rows */
#define DNROWS 8192      /* NEXP*DDIM routed down rows */
#define WQB 4608         /* wquant blocks: 18432/8 + 9216/4 */

// meta: [0..7] counts, [8..15] base[e], [16] total_padded, [30] dtype flag (1=fp32 inputs)

__device__ inline float bf2f(u16 u) {
    union { unsigned int i; float f; } v; v.i = ((unsigned int)u) << 16; return v.f;
}
__device__ inline u16 f2bf(float f) {
    union { float f; unsigned int i; } v; v.f = f;
    unsigned int lsb = (v.i >> 16) & 1u;
    return (u16)((v.i + 0x7fffu + lsb) >> 16);
}
__device__ inline int q8(float v, float inv) {
    int x = (int)rintf(v * inv);
    return x < -127 ? -127 : (x > 127 ? 127 : x);
}

typedef const __attribute__((address_space(1))) void gas_void;
typedef __attribute__((address_space(3))) void las_void;
#define GLL16(g, l) __builtin_amdgcn_global_load_lds((gas_void*)(g), (las_void*)(l), 16, 0, 0)

// Per-block dtype detect over first 1024 halfwords of x.
__device__ inline int detect_inline(const u16* __restrict__ x, int* sh) {
    if (threadIdx.x == 0) *sh = 0;
    __syncthreads();
    const int per = 1024 / blockDim.x;
    int bad = 0;
    for (int i = 0; i < per; i++) {
        u16 v = x[threadIdx.x * per + i];
        if (((v >> 7) & 0xFF) >= 0x8F) bad++;
    }
    if (bad) atomicAdd(sh, bad);
    __syncthreads();
    return (*sh > 32) ? 1 : 0;
}

// ======== Fused: router blocks [0, nrb) + wquant blocks [nrb, nrb+WQB) ========
// Router: 16 tokens/block, fp32 logits -> top2 (no atomics).
// Wquant: GLL16-stage 8 up-rows / 4 down-rows (raw bytes) into 32 KB LDS
// (zero-VGPR async MLP), then per-wave fp32-exact row max + int8 quantize.
__global__ __launch_bounds__(256) void fused_rw_kernel(
    const void* __restrict__ x_, const void* __restrict__ rw_, const void* __restrict__ rb_,
    const void* __restrict__ w_up, const void* __restrict__ w_down,
    const void* __restrict__ sw_up, const void* __restrict__ sw_down,
    float* __restrict__ top_w, int* __restrict__ top_idx,
    char* __restrict__ qup, char* __restrict__ qdn,
    float* __restrict__ su, float* __restrict__ sd, int nrb)
{
    __shared__ char smem[32768 + 16];
    const int tid = threadIdx.x;
    const int wave = tid >> 6, lane = tid & 63;
    const int flag = detect_inline((const u16*)x_, (int*)(smem + 32768));

    if ((int)blockIdx.x < nrb) {
        // ---------------- router path ----------------
        float* rws = (float*)smem;
        if (!flag) {
            const ushort4* rwv = (const ushort4*)rw_;
            #pragma unroll
            for (int i = 0; i < 8; i++) {
                int idx = tid + i * 256;
                ushort4 h = rwv[idx];
                rws[idx * 4 + 0] = bf2f(h.x); rws[idx * 4 + 1] = bf2f(h.y);
                rws[idx * 4 + 2] = bf2f(h.z); rws[idx * 4 + 3] = bf2f(h.w);
            }
        } else {
            const float4* rwv = (const float4*)rw_;
            #pragma unroll
            for (int i = 0; i < 8; i++) {
                int idx = tid + i * 256;
                float4 f = rwv[idx];
                rws[idx * 4 + 0] = f.x; rws[idx * 4 + 1] = f.y;
                rws[idx * 4 + 2] = f.z; rws[idx * 4 + 3] = f.w;
            }
        }
        __syncthreads();

        for (int sub = 0; sub < 4; sub++) {
            const int t = blockIdx.x * 16 + wave * 4 + sub;
            float xv[16];
            if (!flag) {
                const u16* xr = (const u16*)x_ + (size_t)t * DDIM + lane * 16;
                uint4 p0 = *(const uint4*)(xr);
                uint4 p1 = *(const uint4*)(xr + 8);
                #pragma unroll
                for (int d = 0; d < 8; d++) xv[d]     = bf2f(((const u16*)&p0)[d]);
                #pragma unroll
                for (int d = 0; d < 8; d++) xv[d + 8] = bf2f(((const u16*)&p1)[d]);
            } else {
                const float4* xr = (const float4*)((const float*)x_ + (size_t)t * DDIM + lane * 16);
                #pragma unroll
                for (int c = 0; c < 4; c++) {
                    float4 f = xr[c];
                    xv[c * 4 + 0] = f.x; xv[c * 4 + 1] = f.y;
                    xv[c * 4 + 2] = f.z; xv[c * 4 + 3] = f.w;
                }
            }
            float acc[NEXP];
            #pragma unroll
            for (int e = 0; e < NEXP; e++) {
                const float* wr = &rws[e * DDIM + lane * 16];
                float s = 0.f;
                #pragma unroll
                for (int d = 0; d < 16; d++) s += xv[d] * wr[d];
                acc[e] = s;
            }
            #pragma unroll
            for (int e = 0; e < NEXP; e++) {
                #pragma unroll
                for (int off = 32; off > 0; off >>= 1)
                    acc[e] += __shfl_xor(acc[e], off, 64);
            }
            if (lane == 0) {
                float lg[NEXP];
                #pragma unroll
                for (int e = 0; e < NEXP; e++) {
                    float b = flag ? ((const float*)rb_)[e] : bf2f(((const u16*)rb_)[e]);
                    lg[e] = acc[e] + b;
                }
                int i0 = 0;
                #pragma unroll
                for (int e = 1; e < NEXP; e++) if (lg[e] > lg[i0]) i0 = e;
                int i1 = (i0 == 0) ? 1 : 0;
                #pragma unroll
                for (int e = 0; e < NEXP; e++) if (e != i0 && lg[e] > lg[i1]) i1 = e;
                float e1 = __expf(lg[i1] - lg[i0]);
                float w0 = 1.f / (1.f + e1);
                float w1 = e1 / (1.f + e1);
                top_w[2 * t] = w0;  top_w[2 * t + 1] = w1;
                top_idx[2 * t] = i0; top_idx[2 * t + 1] = i1;
            }
        }
        return;
    }

    // ---------------- wquant path ----------------
    const int g = blockIdx.x - nrb;
    const int isUp = (g < 2304);
    const size_t es = flag ? 4 : 2;
    const int G = isUp ? 8 : 4;                      // rows per block
    const int rowelems = isUp ? DDIM : FDIM;
    const size_t rowbytes = (size_t)rowelems * es;   // 2/4/4/8 KB
    const int R0 = isUp ? (g * 8) : ((g - 2304) * 4);
    const char* wbase = isUp ? (const char*)w_up : (const char*)w_down;
    const char* sbase = isUp ? (const char*)sw_up : (const char*)sw_down;
    const int nmain = isUp ? UPROWS : DNROWS;
    char* qdst = isUp ? qup : qdn;
    float* sdst = isUp ? su : sd;

    // async stage G rows into LDS (1 KB per GLL issue, all in flight)
    const int cpr = (int)(rowbytes >> 10);           // 1KB chunks per row (2/4/8)
    const int cprsh = 31 - __clz(cpr);
    const int npw = (G * cpr) >> 2;                  // issues per wave (4/8)
    for (int k = 0; k < npw; k++) {
        const int ii = wave * npw + k;
        const int r = ii >> cprsh;
        const int c = ii - (r << cprsh);
        const int R = R0 + r;
        const char* src = (R < nmain ? wbase + (size_t)R * rowbytes
                                     : sbase + (size_t)(R - nmain) * rowbytes)
                          + (c << 10) + lane * 16;
        GLL16(src, smem + r * rowbytes + (c << 10));
    }
    __syncthreads();

    // each wave reduces + quantizes its own rows
    const int rpw = G >> 2;                          // rows per wave (2 up / 1 down)
    const int cmax = rowelems >> 8;                  // float4-groups per lane (4/8)
    for (int rr = 0; rr < rpw; rr++) {
        const int r = wave * rpw + rr;
        const int R = R0 + r;
        const char* ld = smem + r * rowbytes;
        float m = 0.f;
        if (flag) {
            for (int c = 0; c < cmax; c++) {
                float4 f = *(const float4*)(ld + (size_t)((c * 64 + lane) << 4));
                m = fmaxf(m, fmaxf(fmaxf(fabsf(f.x), fabsf(f.y)),
                                   fmaxf(fabsf(f.z), fabsf(f.w))));
            }
        } else {
            for (int c = 0; c < cmax; c++) {
                ushort4 h = *(const ushort4*)(ld + (size_t)((c * 64 + lane) << 3));
                m = fmaxf(m, fmaxf(fmaxf(fabsf(bf2f(h.x)), fabsf(bf2f(h.y))),
                                   fmaxf(fabsf(bf2f(h.z)), fabsf(bf2f(h.w)))));
            }
        }
        #pragma unroll
        for (int off = 32; off > 0; off >>= 1) m = fmaxf(m, __shfl_xor(m, off, 64));
        m = fmaxf(m, 1e-12f);
        if (lane == 0) sdst[R] = m / 127.f;
        const float inv = 127.f / m;
        for (int c = 0; c < cmax; c++) {
            float4 f;
            if (flag) {
                f = *(const float4*)(ld + (size_t)((c * 64 + lane) << 4));
            } else {
                ushort4 h = *(const ushort4*)(ld + (size_t)((c * 64 + lane) << 3));
                f.x = bf2f(h.x); f.y = bf2f(h.y); f.z = bf2f(h.z); f.w = bf2f(h.w);
            }
            unsigned u = (unsigned)(q8(f.x, inv) & 255) |
                         ((unsigned)(q8(f.y, inv) & 255) << 8) |
                         ((unsigned)(q8(f.z, inv) & 255) << 16) |
                         ((unsigned)(q8(f.w, inv) & 255) << 24);
            *(unsigned*)(qdst + (size_t)R * rowelems + (size_t)((c * 64 + lane) << 2)) = u;
        }
    }
}

// -------- Rank: prefix-sum rows per expert; publishes dtype flag --------
__global__ __launch_bounds__(1024) void rank_kernel(
    const u16* __restrict__ x, const int* __restrict__ top_idx,
    int* __restrict__ tok_rows, int* __restrict__ meta)
{
    __shared__ int wsum[16][NEXP];
    __shared__ int wbase[16][NEXP];
    __shared__ int scnt;
    const int tid = threadIdx.x, lane = tid & 63, wave = tid >> 6;

    const int flag = detect_inline(x, &scnt);
    if (tid == 0) meta[30] = flag;

    const int4* tp = (const int4*)(top_idx + tid * 8);
    int4 v0 = tp[0], v1 = tp[1];
    int e[8] = { v0.x, v0.y, v0.z, v0.w, v1.x, v1.y, v1.z, v1.w };

    int tcnt[NEXP];
    #pragma unroll
    for (int en = 0; en < NEXP; en++) tcnt[en] = 0;
    #pragma unroll
    for (int j = 0; j < 8; j++)
        #pragma unroll
        for (int en = 0; en < NEXP; en++) tcnt[en] += (e[j] == en);

    int excl[NEXP];
    #pragma unroll
    for (int en = 0; en < NEXP; en++) {
        int v = tcnt[en];
        #pragma unroll
        for (int off = 1; off < 64; off <<= 1) {
            int u = __shfl_up(v, off, 64);
            if (lane >= off) v += u;
        }
        excl[en] = v - tcnt[en];
        if (lane == 63) wsum[wave][en] = v;
    }
    __syncthreads();
    if (tid < NEXP) {
        int s = 0;
        for (int w = 0; w < 16; w++) { int c = wsum[w][tid]; wbase[w][tid] = s; s += c; }
        meta[tid] = s;
    }
    __syncthreads();
    if (tid == 0) {
        int b = 0;
        for (int en = 0; en < NEXP; en++) {
            meta[8 + en] = b;
            b += ((meta[en] + 127) >> 7) << 7;
        }
        meta[16] = b;
    }
    __syncthreads();

    int cur[NEXP];
    #pragma unroll
    for (int en = 0; en < NEXP; en++) cur[en] = meta[8 + en] + wbase[wave][en] + excl[en];

    int r[8];
    #pragma unroll
    for (int j = 0; j < 8; j++) {
        int rr = 0;
        #pragma unroll
        for (int en = 0; en < NEXP; en++)
            if (e[j] == en) { rr = cur[en]; cur[en] = rr + 1; }
        r[j] = rr;
    }
    int4* rp = (int4*)(tok_rows + tid * 8);
    rp[0] = make_int4(r[0], r[1], r[2], r[3]);
    rp[1] = make_int4(r[4], r[5], r[6], r[7]);
}

// -------- Gather + per-token int8 quantize: x rows -> xq + sxa --------
__global__ __launch_bounds__(128) void gather_q_kernel(
    const void* __restrict__ x_, const int* __restrict__ tok_rows,
    char* __restrict__ xq, float* __restrict__ sxa, const int* __restrict__ meta)
{
    __shared__ float red[128];
    const int t = blockIdx.x, tid = threadIdx.x;
    const int r0 = tok_rows[2 * t], r1 = tok_rows[2 * t + 1];

    float v[8];
    if (!meta[30]) {
        uint4 p = ((const uint4*)((const u16*)x_ + (size_t)t * DDIM))[tid];
        #pragma unroll
        for (int d = 0; d < 8; d++) v[d] = bf2f(((const u16*)&p)[d]);
    } else {
        const float4* xf = (const float4*)((const float*)x_ + (size_t)t * DDIM);
        float4 a = xf[2 * tid], b = xf[2 * tid + 1];
        v[0] = a.x; v[1] = a.y; v[2] = a.z; v[3] = a.w;
        v[4] = b.x; v[5] = b.y; v[6] = b.z; v[7] = b.w;
    }
    float m = 0.f;
    #pragma unroll
    for (int d = 0; d < 8; d++) m = fmaxf(m, fabsf(v[d]));
    red[tid] = m;
    __syncthreads();
    for (int s = 64; s > 0; s >>= 1) {
        if (tid < s) red[tid] = fmaxf(red[tid], red[tid + s]);
        __syncthreads();
    }
    const float mx = fmaxf(red[0], 1e-8f);
    const float inv = 127.f / mx;

    uint2 u;
    u.x = (unsigned)(q8(v[0], inv) & 255) | ((unsigned)(q8(v[1], inv) & 255) << 8) |
          ((unsigned)(q8(v[2], inv) & 255) << 16) | ((unsigned)(q8(v[3], inv) & 255) << 24);
    u.y = (unsigned)(q8(v[4], inv) & 255) | ((unsigned)(q8(v[5], inv) & 255) << 8) |
          ((unsigned)(q8(v[6], inv) & 255) << 16) | ((unsigned)(q8(v[7], inv) & 255) << 24);

    ((uint2*)(xq + (size_t)r0 * DDIM))[tid] = u;
    ((uint2*)(xq + (size_t)r1 * DDIM))[tid] = u;
    ((uint2*)(xq + (size_t)(SHOFF + t) * DDIM))[tid] = u;
    if (tid == 0) {
        float s = mx / 127.f;
        sxa[r0] = s; sxa[r1] = s; sxa[SHOFF + t] = s;
    }
}

// ------- Grouped int8 GEMM: 128x256 tile, BK=64, waves 64x128, dbuf GLL16 ----
// mfma_i32_16x16x64_i8. LDS slot swizzle kills bank conflicts.
// XCD swizzle: L%8 owns a 13-rt band, ct outer / rt inner; grid = 8*13*NCT.
__global__ __launch_bounds__(256, 2) void moe_gemm_i8(
    const char* __restrict__ A, const char* __restrict__ Wq,
    const float* __restrict__ sa, const float* __restrict__ sw,
    u16* __restrict__ Cout, const int* __restrict__ meta, int N, int Kd, int act)
{
    const int L = blockIdx.y * gridDim.x + blockIdx.x;
    const int xcd = L & 7;
    const int jj = L >> 3;
    const int rt = xcd * 13 + (jj % 13);
    const int ct = jj / 13;

    int e;
    if (rt >= RT_TILES) {
        e = NEXP;
    } else {
        const int r0t = rt * 128;
        if (r0t >= meta[16]) return;
        e = 0;
        #pragma unroll
        for (int i = 1; i < NEXP; i++) if (r0t >= meta[8 + i]) e = i;
        if (r0t >= meta[8 + e] + meta[e]) return;
    }
    const char* Wb = Wq + (size_t)(e * N + ct * 256) * Kd;
    const float* swb = sw + e * N + ct * 256;

    __shared__ char As[2][128 * 64];   // 16 KB
    __shared__ char Bs[2][256 * 64];   // 32 KB

    const int tid = threadIdx.x;
    const int wave = tid >> 6, lane = tid & 63;
    const int wm = (wave >> 1) * 64;    // 0 / 64
    const int wn = (wave & 1) * 128;    // 0 / 128
    const int l16 = lane & 15;
    const int q = lane >> 4;
    const int slot = (q + (l16 >> 1)) & 3;

    const int rsub = lane >> 2;                        // 0..15
    const int qs = ((lane & 3) - ((lane >> 3) & 3)) & 3;

    const char* Ag = A + (size_t)(rt * 128 + wave * 16 + rsub) * Kd + qs * 16;
    const char* Bg = Wb + (size_t)(wave * 16 + rsub) * Kd + qs * 16;
    const size_t rstep = (size_t)64 * Kd;

    i32x4 acc[4][8] = {};

#define STAGE(buf, off) do { \
        GLL16(Ag + (off),             &As[buf][wave * 1024]); \
        GLL16(Ag + (off) + rstep,     &As[buf][4096 + wave * 1024]); \
        GLL16(Bg + (off),             &Bs[buf][wave * 1024]); \
        GLL16(Bg + (off) + rstep,     &Bs[buf][4096 + wave * 1024]); \
        GLL16(Bg + (off) + 2 * rstep, &Bs[buf][8192 + wave * 1024]); \
        GLL16(Bg + (off) + 3 * rstep, &Bs[buf][12288 + wave * 1024]); \
    } while (0)

    STAGE(0, 0);
    __syncthreads();

    int cur = 0;
    for (int kk = 0; kk < Kd; kk += 64) {
        if (kk + 64 < Kd) STAGE(cur ^ 1, kk + 64);
        i32x4 af[4], bf[8];
        #pragma unroll
        for (int i = 0; i < 4; i++)
            af[i] = *(const i32x4*)&As[cur][(wm + i * 16 + l16) * 64 + slot * 16];
        #pragma unroll
        for (int j = 0; j < 8; j++)
            bf[j] = *(const i32x4*)&Bs[cur][(wn + j * 16 + l16) * 64 + slot * 16];
        #pragma unroll
        for (int i = 0; i < 4; i++)
            #pragma unroll
            for (int j = 0; j < 8; j++)
                acc[i][j] = __builtin_amdgcn_mfma_i32_16x16x64_i8(af[i], bf[j], acc[i][j], 0, 0, 0);
        __syncthreads();
        cur ^= 1;
    }
#undef STAGE

    float sal[4][4];
    #pragma unroll
    for (int i = 0; i < 4; i++)
        #pragma unroll
        for (int rr = 0; rr < 4; rr++)
            sal[i][rr] = sa[rt * 128 + wm + i * 16 + q * 4 + rr];
    float swl[8];
    #pragma unroll
    for (int j = 0; j < 8; j++) swl[j] = swb[wn + j * 16 + l16];

    u16* Crow = Cout + (size_t)(rt * 128) * N + ct * 256;
    #pragma unroll
    for (int i = 0; i < 4; i++) {
        #pragma unroll
        for (int j = 0; j < 8; j++) {
            #pragma unroll
            for (int rr = 0; rr < 4; rr++) {
                const int row = wm + i * 16 + q * 4 + rr;
                const int col = wn + j * 16 + l16;
                float v = (float)acc[i][j][rr] * sal[i][rr] * swl[j];
                if (act) v = v / (1.f + __expf(-v));   // SiLU
                Crow[(size_t)row * N + col] = f2bf(v);
            }
        }
    }
}

// -------- h quantize: hg bf16 rows -> h8 int8 + sh (per gathered row) --------
__global__ __launch_bounds__(256) void hquant_kernel(
    const u16* __restrict__ hg, char* __restrict__ h8, float* __restrict__ sh,
    const int* __restrict__ meta)
{
    const int r = blockIdx.x;
    if (r >= meta[16] && r < SHOFF) return;   // skip inter-segment pad
    __shared__ float red[256];
    const int tid = threadIdx.x;
    const u16* row = hg + (size_t)r * FDIM;
    uint4 p = ((const uint4*)row)[tid];
    float v[8];
    #pragma unroll
    for (int d = 0; d < 8; d++) v[d] = bf2f(((const u16*)&p)[d]);
    float m = 0.f;
    #pragma unroll
    for (int d = 0; d < 8; d++) m = fmaxf(m, fabsf(v[d]));
    red[tid] = m;
    __syncthreads();
    for (int s = 128; s > 0; s >>= 1) {
        if (tid < s) red[tid] = fmaxf(red[tid], red[tid + s]);
        __syncthreads();
    }
    const float mx = fmaxf(red[0], 1e-8f);
    const float inv = 127.f / mx;
    if (tid == 0) sh[r] = mx / 127.f;
    uint2 u;
    u.x = (unsigned)(q8(v[0], inv) & 255) | ((unsigned)(q8(v[1], inv) & 255) << 8) |
          ((unsigned)(q8(v[2], inv) & 255) << 16) | ((unsigned)(q8(v[3], inv) & 255) << 24);
    u.y = (unsigned)(q8(v[4], inv) & 255) | ((unsigned)(q8(v[5], inv) & 255) << 8) |
          ((unsigned)(q8(v[6], inv) & 255) << 16) | ((unsigned)(q8(v[7], inv) & 255) << 24);
    ((uint2*)(h8 + (size_t)r * FDIM))[tid] = u;
}

// ---------------- Combine ----------------
__global__ __launch_bounds__(256) void combine_kernel(
    const u16* __restrict__ yg, const float* __restrict__ top_w,
    const int* __restrict__ tok_rows, void* __restrict__ out_, const int* __restrict__ meta)
{
    const int t = blockIdx.x;
    const int r0 = tok_rows[2 * t], r1 = tok_rows[2 * t + 1];
    const float w0 = top_w[2 * t], w1 = top_w[2 * t + 1];
    const int d = threadIdx.x * 4;
    ushort4 y0 = *(const ushort4*)(yg + (size_t)r0 * DDIM + d);
    ushort4 y1 = *(const ushort4*)(yg + (size_t)r1 * DDIM + d);
    ushort4 ys = *(const ushort4*)(yg + (size_t)(SHOFF + t) * DDIM + d);
    float o0 = w0 * bf2f(y0.x) + w1 * bf2f(y1.x) + bf2f(ys.x);
    float o1 = w0 * bf2f(y0.y) + w1 * bf2f(y1.y) + bf2f(ys.y);
    float o2 = w0 * bf2f(y0.z) + w1 * bf2f(y1.z) + bf2f(ys.z);
    float o3 = w0 * bf2f(y0.w) + w1 * bf2f(y1.w) + bf2f(ys.w);
    if (!meta[30]) {
        ushort4 o; o.x = f2bf(o0); o.y = f2bf(o1); o.z = f2bf(o2); o.w = f2bf(o3);
        *(ushort4*)((u16*)out_ + (size_t)t * DDIM + d) = o;
    } else {
        float4 o; o.x = o0; o.y = o1; o.z = o2; o.w = o3;
        *(float4*)((float*)out_ + (size_t)t * DDIM + d) = o;
    }
}

extern "C" void kernel_launch(void* const* d_in, const int* in_sizes, int n_in,
                              void* d_out, int out_size, void* d_ws, size_t ws_size,
                              hipStream_t stream) {
    const void* x       = d_in[0];
    const void* rw      = d_in[1];
    const void* rb      = d_in[2];
    const void* w_up    = d_in[3];
    const void* w_down  = d_in[4];
    const void* sw_up   = d_in[5];
    const void* sw_down = d_in[6];

    const int T = in_sizes[0] / DDIM;  // 4096

    char* ws = (char*)d_ws;
    int*   meta     = (int*)ws;
    float* top_w    = (float*)(ws + 1024);
    int*   top_idx  = (int*)(ws + 1024 + 8 * T);
    int*   tok_rows = (int*)(ws + 1024 + 16 * T);
    size_t off = 131072;
    u16*  yg = (u16*)(ws + off);            // down output (bf16)
    char* xq = (char*)(ws + off);           // aliased: xq dead before yg written
    off += (size_t)RCAP * DDIM * 2;
    u16*  hg = (u16*)(ws + off);            // up output (bf16)
    off += (size_t)RCAP * FDIM * 2;
    char* h8 = (char*)(ws + off);
    off += (size_t)RCAP * FDIM;
    char* qup = (char*)(ws + off);
    off += (size_t)(NEXP + 1) * FDIM * DDIM;
    char* qdn = (char*)(ws + off);
    off += (size_t)(NEXP + 1) * DDIM * FDIM;
    float* sxa = (float*)(ws + off); off += (size_t)RCAP * 4;
    float* sh  = (float*)(ws + off); off += (size_t)RCAP * 4;
    float* su  = (float*)(ws + off); off += (size_t)(NEXP + 1) * FDIM * 4;
    float* sd  = (float*)(ws + off); off += (size_t)(NEXP + 1) * DDIM * 4;

    const int nrb = T / 16;  // 256 router blocks, placed first in the fused grid
    fused_rw_kernel<<<nrb + WQB, 256, 0, stream>>>(
        x, rw, rb, w_up, w_down, sw_up, sw_down,
        top_w, top_idx, qup, qdn, su, sd, nrb);
    rank_kernel<<<1, 1024, 0, stream>>>((const u16*)x, top_idx, tok_rows, meta);
    gather_q_kernel<<<T, 128, 0, stream>>>(x, tok_rows, xq, sxa, meta);

    // Up: [RCAP,1024]i8 x [9*2048,1024]i8 -> hg bf16 (SiLU fused)
    // grid 8x104 = 832 = 8 XCD * 13 rt * 8 ct  (matches L-decode)
    moe_gemm_i8<<<dim3(FDIM / 256, NRT), 256, 0, stream>>>(
        xq, qup, sxa, su, hg, meta, FDIM, DDIM, 1);
    hquant_kernel<<<RCAP, 256, 0, stream>>>(hg, h8, sh, meta);
    // Down: grid 4x104 = 416 = 8 XCD * 13 rt * 4 ct
    moe_gemm_i8<<<dim3(DDIM / 256, NRT), 256, 0, stream>>>(
        h8, qdn, sh, sd, yg, meta, DDIM, FDIM, 0);
    combine_kernel<<<T, 256, 0, stream>>>(yg, top_w, tok_rows, d_out, meta);
}